// Round 1
// baseline (683.768 us; speedup 1.0000x reference)
//
#include <hip/hip_runtime.h>
#include <math.h>

// ---------- types ----------
typedef __bf16 bf16_t;
typedef bf16_t bf16x8 __attribute__((ext_vector_type(8)));
typedef float  f32x4  __attribute__((ext_vector_type(4)));
typedef unsigned short ushortx4 __attribute__((ext_vector_type(4)));

#define MFMA16(a, b, c) __builtin_amdgcn_mfma_f32_16x16x32_bf16((a), (b), (c), 0, 0, 0)

__device__ __forceinline__ unsigned short f2bf(float f) {
    unsigned int u = __float_as_uint(f);
    u = (u + 0x7fffu + ((u >> 16) & 1u)) >> 16;
    return (unsigned short)u;
}

// ---------- sizes ----------
// B=2, L=2048, D_MODEL=1024, H=16, DH=64, HB=32
// ws layout (bytes):
//  qb 0..8M, kb 8..16M, vb 16..24M   (bf16 copies of inputs, [b*2048+l][1024])
//  wqt 24M, wkt 26M, wvt 28M         (bf16, [h][e][d] 16x64x1024)
//  wot 30M                           (bf16, [n][k] 1024x1024)
//  qh 32M, kh 40M                    (bf16, [hb][l][64])
//  vt 48M                            (bf16, [hb][e][l] 32x64x2048)
//  ao 56M                            (bf16, [b*2048+l][1024])
//  x  64M..80M                       (fp32, [b*2048+l][1024])

// ---------- elementwise fp32 -> bf16 ----------
__global__ __launch_bounds__(256) void k_cvt(const float* __restrict__ src,
                                             unsigned short* __restrict__ dst, int n4) {
    int i = blockIdx.x * 256 + threadIdx.x;
    if (i < n4) {
        float4 v = ((const float4*)src)[i];
        ushortx4 r;
        r[0] = f2bf(v.x); r[1] = f2bf(v.y); r[2] = f2bf(v.z); r[3] = f2bf(v.w);
        ((ushortx4*)dst)[i] = r;
    }
}

// ---------- transpose + convert: src [H][R][C] fp32 -> dst [H][C][R] bf16 ----------
__global__ __launch_bounds__(256) void k_tcvt(const float* __restrict__ src,
                                              unsigned short* __restrict__ dst,
                                              int R, int C) {
    __shared__ float tile[32][33];
    int h = blockIdx.z;
    int r0 = blockIdx.x * 32, c0 = blockIdx.y * 32;
    int tx = threadIdx.x & 31, ty = threadIdx.x >> 5;  // 32 x 8
    const float* s = src + ((size_t)h * R + r0) * C + c0;
#pragma unroll
    for (int i = 0; i < 4; ++i) tile[ty + i * 8][tx] = s[(ty + i * 8) * (size_t)C + tx];
    __syncthreads();
    unsigned short* d = dst + ((size_t)h * C + c0) * R + r0;
#pragma unroll
    for (int i = 0; i < 4; ++i) d[(ty + i * 8) * (size_t)R + tx] = f2bf(tile[tx][ty + i * 8]);
}

// ---------- unified NT projection GEMM ----------
// C[m][n] = sum_k A[m][k] * Bn[n][k]  (both row-major in k, K=1024)
// z=0: qh, z=1: kh, z=2: vt (roles swapped so stores stay coalesced)
__global__ __launch_bounds__(256) void k_gemm_qkv(
    const unsigned short* __restrict__ qb, const unsigned short* __restrict__ kb,
    const unsigned short* __restrict__ vb, const unsigned short* __restrict__ wqt,
    const unsigned short* __restrict__ wkt, const unsigned short* __restrict__ wvt,
    unsigned short* __restrict__ qh, unsigned short* __restrict__ kh,
    unsigned short* __restrict__ vt) {
    int tile = blockIdx.x;  // 0..31
    int hb   = blockIdx.y;  // 0..31  (= h*2 + b)
    int z    = blockIdx.z;  // 0..2
    int h = hb >> 1, b = hb & 1;
    int wave = threadIdx.x >> 6, lane = threadIdx.x & 63;
    int l15 = lane & 15, quad = lane >> 4;

    const unsigned short *Abase, *Bbase;
    unsigned short* outp;
    int sm;
    if (z == 0) {
        Abase = qb + ((size_t)(b * 2048 + tile * 64)) * 1024;
        Bbase = wqt + (size_t)h * 65536;
        outp  = qh + ((size_t)(hb * 2048 + tile * 64)) * 64; sm = 64;
    } else if (z == 1) {
        Abase = kb + ((size_t)(b * 2048 + tile * 64)) * 1024;
        Bbase = wkt + (size_t)h * 65536;
        outp  = kh + ((size_t)(hb * 2048 + tile * 64)) * 64; sm = 64;
    } else {
        Abase = wvt + (size_t)h * 65536;                        // rows = e (64)
        Bbase = vb + ((size_t)(b * 2048 + tile * 64)) * 1024;   // n-rows = l
        outp  = vt + (size_t)hb * 131072 + tile * 64; sm = 2048;
    }
    const unsigned short* A  = Abase + (wave * 16 + l15) * 1024 + quad * 8;
    const unsigned short* Bp = Bbase + l15 * 1024 + quad * 8;

    f32x4 acc[4] = {};
    for (int k0 = 0; k0 < 1024; k0 += 32) {
        bf16x8 af = *(const bf16x8*)(A + k0);
#pragma unroll
        for (int t = 0; t < 4; ++t) {
            bf16x8 bf = *(const bf16x8*)(Bp + t * 16 * 1024 + k0);
            acc[t] = MFMA16(af, bf, acc[t]);
        }
    }
#pragma unroll
    for (int t = 0; t < 4; ++t)
#pragma unroll
        for (int r = 0; r < 4; ++r) {
            int m = wave * 16 + quad * 4 + r;      // local row
            int n = t * 16 + l15;                  // local col
            outp[(size_t)m * sm + n] = f2bf(acc[t][r]);
        }
}

// ---------- flash attention ----------
// grid (32 qtiles, 32 hb), block 256 (4 waves x 16 Q-rows)
__global__ __launch_bounds__(256) void k_attn(
    const unsigned short* __restrict__ qh, const unsigned short* __restrict__ kh,
    const unsigned short* __restrict__ vt, const int* __restrict__ mask,
    unsigned short* __restrict__ ao) {
    int qt = blockIdx.x, hb = blockIdx.y;
    int h = hb >> 1, b = hb & 1;
    int wave = threadIdx.x >> 6, lane = threadIdx.x & 63;
    int l15 = lane & 15, quad = lane >> 4;

    __shared__ unsigned short Pl[4][16][72];  // per-wave P buffer, padded row stride

    const unsigned short* Qb =
        qh + ((size_t)(hb * 2048 + qt * 64 + wave * 16 + l15)) * 64 + quad * 8;
    bf16x8 qf0 = *(const bf16x8*)(Qb);
    bf16x8 qf1 = *(const bf16x8*)(Qb + 32);

    const unsigned short* Kb = kh + (size_t)hb * 131072 + l15 * 64 + quad * 8;
    const unsigned short* Vb = vt + (size_t)hb * 131072 + l15 * 2048 + quad * 8;
    const int* Mb = mask + ((size_t)(b * 2048 + qt * 64 + wave * 16 + quad * 4)) * 2048 + l15;

    f32x4 o[4] = {};
    float mrow[4], lrow[4];
#pragma unroll
    for (int r = 0; r < 4; ++r) { mrow[r] = -1e30f; lrow[r] = 0.f; }
    const float scale = 0.125f;  // 1/sqrt(64)

    for (int kt = 0; kt < 32; ++kt) {
        // ---- S = Q @ K^T (16x64 per wave) ----
        f32x4 s[4] = {};
#pragma unroll
        for (int t = 0; t < 4; ++t) {
            const unsigned short* kp = Kb + (size_t)(kt * 64 + t * 16) * 64;
            bf16x8 b0 = *(const bf16x8*)(kp);
            bf16x8 b1 = *(const bf16x8*)(kp + 32);
            s[t] = MFMA16(qf0, b0, s[t]);
            s[t] = MFMA16(qf1, b1, s[t]);
        }
        // ---- scale + mask ----
#pragma unroll
        for (int t = 0; t < 4; ++t) {
            const int* mp = Mb + kt * 64 + t * 16;
#pragma unroll
            for (int r = 0; r < 4; ++r) {
                int msk = mp[(size_t)r * 2048];
                float v = s[t][r] * scale;
                s[t][r] = msk ? -1e30f : v;
            }
        }
        // ---- online softmax: row max over 64 cols (16 lanes x 4 ntiles) ----
        float mnew[4], alpha[4], psum[4];
#pragma unroll
        for (int r = 0; r < 4; ++r) {
            float mx = fmaxf(fmaxf(s[0][r], s[1][r]), fmaxf(s[2][r], s[3][r]));
#pragma unroll
            for (int off = 8; off; off >>= 1) mx = fmaxf(mx, __shfl_xor(mx, off, 64));
            mnew[r] = fmaxf(mrow[r], mx);
            alpha[r] = __expf(mrow[r] - mnew[r]);
            mrow[r] = mnew[r];
            psum[r] = 0.f;
        }
#pragma unroll
        for (int t = 0; t < 4; ++t)
#pragma unroll
            for (int r = 0; r < 4; ++r) {
                float p = __expf(s[t][r] - mnew[r]);
                psum[r] += p;
                Pl[wave][quad * 4 + r][t * 16 + l15] = f2bf(p);
            }
#pragma unroll
        for (int r = 0; r < 4; ++r) {
            float ps = psum[r];
#pragma unroll
            for (int off = 8; off; off >>= 1) ps += __shfl_xor(ps, off, 64);
            lrow[r] = lrow[r] * alpha[r] + ps;
        }
#pragma unroll
        for (int t = 0; t < 4; ++t) {
            f32x4 ov = o[t];
#pragma unroll
            for (int r = 0; r < 4; ++r) ov[r] *= alpha[r];
            o[t] = ov;
        }
        // ---- O += P @ V  (P via wave-private LDS transpose; V from vt) ----
#pragma unroll
        for (int kc = 0; kc < 2; ++kc) {
            bf16x8 pf = *(const bf16x8*)(&Pl[wave][l15][kc * 32 + quad * 8]);
#pragma unroll
            for (int t = 0; t < 4; ++t) {
                bf16x8 vf = *(const bf16x8*)(Vb + (size_t)(t * 16) * 2048 + kt * 64 + kc * 32);
                o[t] = MFMA16(pf, vf, o[t]);
            }
        }
    }
    // ---- normalize + store to ao[b*2048+l][h*64+e] ----
#pragma unroll
    for (int r = 0; r < 4; ++r) {
        float inv = 1.0f / lrow[r];
        int m = qt * 64 + wave * 16 + quad * 4 + r;
#pragma unroll
        for (int t = 0; t < 4; ++t) {
            int e = t * 16 + l15;
            ao[((size_t)(b * 2048 + m)) * 1024 + h * 64 + e] = f2bf(o[t][r] * inv);
        }
    }
}

// ---------- output projection + bias + residual ----------
__global__ __launch_bounds__(256) void k_gemm_out(
    const unsigned short* __restrict__ ao, const unsigned short* __restrict__ wot,
    const float* __restrict__ bo, const float* __restrict__ resid,
    float* __restrict__ xbuf) {
    int mt = blockIdx.x, nt = blockIdx.y;
    int wave = threadIdx.x >> 6, lane = threadIdx.x & 63;
    int l15 = lane & 15, quad = lane >> 4;
    const unsigned short* A  = ao + ((size_t)(mt * 64 + wave * 16 + l15)) * 1024 + quad * 8;
    const unsigned short* Bp = wot + ((size_t)(nt * 64 + l15)) * 1024 + quad * 8;
    f32x4 acc[4] = {};
    for (int k0 = 0; k0 < 1024; k0 += 32) {
        bf16x8 af = *(const bf16x8*)(A + k0);
#pragma unroll
        for (int t = 0; t < 4; ++t) {
            bf16x8 bf = *(const bf16x8*)(Bp + t * 16 * 1024 + k0);
            acc[t] = MFMA16(af, bf, acc[t]);
        }
    }
#pragma unroll
    for (int t = 0; t < 4; ++t) {
        int n = nt * 64 + t * 16 + l15;
        float bov = bo[n];
#pragma unroll
        for (int r = 0; r < 4; ++r) {
            int m = mt * 64 + wave * 16 + quad * 4 + r;
            xbuf[(size_t)m * 1024 + n] = acc[t][r] + bov + resid[(size_t)m * 1024 + n];
        }
    }
}

// ---------- layernorm (torch: std ddof=1, eps on std) ----------
__global__ __launch_bounds__(256) void k_ln(const float* __restrict__ x,
                                            const float* __restrict__ gamma,
                                            const float* __restrict__ beta,
                                            float* __restrict__ out) {
    int row = blockIdx.x;
    const float* xr = x + (size_t)row * 1024;
    float4 v = ((const float4*)xr)[threadIdx.x];
    float s = v.x + v.y + v.z + v.w;
    float ss = v.x * v.x + v.y * v.y + v.z * v.z + v.w * v.w;
#pragma unroll
    for (int off = 32; off; off >>= 1) {
        s += __shfl_down(s, off, 64);
        ss += __shfl_down(ss, off, 64);
    }
    __shared__ float sb[8];
    int wave = threadIdx.x >> 6, lane = threadIdx.x & 63;
    if (lane == 0) { sb[wave] = s; sb[4 + wave] = ss; }
    __syncthreads();
    s = sb[0] + sb[1] + sb[2] + sb[3];
    ss = sb[4] + sb[5] + sb[6] + sb[7];
    float mean = s * (1.0f / 1024.0f);
    float var = fmaxf((ss - 1024.0f * mean * mean) * (1.0f / 1023.0f), 0.f);
    float inv = 1.0f / (sqrtf(var) + 1e-3f);
    float4 g = ((const float4*)gamma)[threadIdx.x];
    float4 bt = ((const float4*)beta)[threadIdx.x];
    float4 o;
    o.x = (v.x - mean) * inv * g.x + bt.x;
    o.y = (v.y - mean) * inv * g.y + bt.y;
    o.z = (v.z - mean) * inv * g.z + bt.z;
    o.w = (v.w - mean) * inv * g.w + bt.w;
    ((float4*)(out + (size_t)row * 1024))[threadIdx.x] = o;
}

// ---------- launch ----------
extern "C" void kernel_launch(void* const* d_in, const int* in_sizes, int n_in,
                              void* d_out, int out_size, void* d_ws, size_t ws_size,
                              hipStream_t stream) {
    const float* v_in  = (const float*)d_in[0];
    const float* k_in  = (const float*)d_in[1];
    const float* q_in  = (const float*)d_in[2];
    const int*   mask  = (const int*)d_in[3];
    const float* w_q   = (const float*)d_in[4];
    const float* w_k   = (const float*)d_in[5];
    const float* w_v   = (const float*)d_in[6];
    const float* w_o   = (const float*)d_in[7];
    const float* b_o   = (const float*)d_in[8];
    const float* gamma = (const float*)d_in[9];
    const float* beta  = (const float*)d_in[10];
    float* out = (float*)d_out;

    char* ws = (char*)d_ws;
    const size_t MB = 1ull << 20;
    unsigned short* qb  = (unsigned short*)(ws + 0 * MB);
    unsigned short* kb  = (unsigned short*)(ws + 8 * MB);
    unsigned short* vb  = (unsigned short*)(ws + 16 * MB);
    unsigned short* wqt = (unsigned short*)(ws + 24 * MB);
    unsigned short* wkt = (unsigned short*)(ws + 26 * MB);
    unsigned short* wvt = (unsigned short*)(ws + 28 * MB);
    unsigned short* wot = (unsigned short*)(ws + 30 * MB);
    unsigned short* qh  = (unsigned short*)(ws + 32 * MB);
    unsigned short* kh  = (unsigned short*)(ws + 40 * MB);
    unsigned short* vt  = (unsigned short*)(ws + 48 * MB);
    unsigned short* ao  = (unsigned short*)(ws + 56 * MB);
    float*          xb  = (float*)(ws + 64 * MB);

    // 1) convert inputs to bf16
    k_cvt<<<dim3(4096), dim3(256), 0, stream>>>(q_in, qb, 1048576);
    k_cvt<<<dim3(4096), dim3(256), 0, stream>>>(k_in, kb, 1048576);
    k_cvt<<<dim3(4096), dim3(256), 0, stream>>>(v_in, vb, 1048576);
    // 2) transpose-convert weights
    k_tcvt<<<dim3(32, 2, 16), dim3(256), 0, stream>>>(w_q, wqt, 1024, 64);
    k_tcvt<<<dim3(32, 2, 16), dim3(256), 0, stream>>>(w_k, wkt, 1024, 64);
    k_tcvt<<<dim3(32, 2, 16), dim3(256), 0, stream>>>(w_v, wvt, 1024, 64);
    k_tcvt<<<dim3(32, 32, 1), dim3(256), 0, stream>>>(w_o, wot, 1024, 1024);
    // 3) q/k/v head projections
    k_gemm_qkv<<<dim3(32, 32, 3), dim3(256), 0, stream>>>(qb, kb, vb, wqt, wkt, wvt,
                                                          qh, kh, vt);
    // 4) flash attention
    k_attn<<<dim3(32, 32), dim3(256), 0, stream>>>(qh, kh, vt, mask, ao);
    // 5) output projection + bias + residual
    k_gemm_out<<<dim3(64, 16), dim3(256), 0, stream>>>(ao, wot, b_o, k_in, xb);
    // 6) layernorm
    k_ln<<<dim3(4096), dim3(256), 0, stream>>>(xb, gamma, beta, out);
}

// Round 2
// 623.034 us; speedup vs baseline: 1.0975x; 1.0975x over previous
//
#include <hip/hip_runtime.h>
#include <math.h>

// ---------- types ----------
typedef __bf16 bf16_t;
typedef bf16_t bf16x8 __attribute__((ext_vector_type(8)));
typedef float  f32x4  __attribute__((ext_vector_type(4)));
typedef unsigned short ushortx4 __attribute__((ext_vector_type(4)));

#define MFMA16(a, b, c) __builtin_amdgcn_mfma_f32_16x16x32_bf16((a), (b), (c), 0, 0, 0)

__device__ __forceinline__ unsigned short f2bf(float f) {
    unsigned int u = __float_as_uint(f);
    u = (u + 0x7fffu + ((u >> 16) & 1u)) >> 16;
    return (unsigned short)u;
}

// B=2, L=2048, D_MODEL=1024, H=16, DH=64, HB=32
// ws layout (bytes):
//  qb 0..8M, kb 8..16M, vb 16..24M   (bf16 [b*2048+l][1024])
//  wqt 24M, wkt 26M, wvt 28M         (bf16 [h][e][d])
//  wot 30M                           (bf16 [n][k])
//  qh 32M, kh 40M                    (bf16 [hb][l][64])
//  vt 48M                            (bf16 [hb][e][l])
//  ao 56M                            (bf16 [b*2048+l][1024])
//  mask64 64M (1MB, dead after attn) then xb 64M..80M (fp32) overwrites it

// ---------- fused fp32 -> bf16 for q,k,v ----------
__global__ __launch_bounds__(256) void k_cvt3(const float* __restrict__ q,
                                              const float* __restrict__ k,
                                              const float* __restrict__ v,
                                              unsigned short* __restrict__ qb,
                                              unsigned short* __restrict__ kb,
                                              unsigned short* __restrict__ vb) {
    int i = blockIdx.x * 256 + threadIdx.x;
    int sel = blockIdx.y;
    const float* src = sel == 0 ? q : (sel == 1 ? k : v);
    unsigned short* dst = sel == 0 ? qb : (sel == 1 ? kb : vb);
    float4 val = ((const float4*)src)[i];
    ushortx4 r;
    r[0] = f2bf(val.x); r[1] = f2bf(val.y); r[2] = f2bf(val.z); r[3] = f2bf(val.w);
    ((ushortx4*)dst)[i] = r;
}

// ---------- transpose + convert: src [H][R][C] fp32 -> dst [H][C][R] bf16 ----------
__global__ __launch_bounds__(256) void k_tcvt(const float* __restrict__ src,
                                              unsigned short* __restrict__ dst,
                                              int R, int C) {
    __shared__ float tile[32][33];
    int h = blockIdx.z;
    int r0 = blockIdx.x * 32, c0 = blockIdx.y * 32;
    int tx = threadIdx.x & 31, ty = threadIdx.x >> 5;
    const float* s = src + ((size_t)h * R + r0) * C + c0;
#pragma unroll
    for (int i = 0; i < 4; ++i) tile[ty + i * 8][tx] = s[(ty + i * 8) * (size_t)C + tx];
    __syncthreads();
    unsigned short* d = dst + ((size_t)h * C + c0) * R + r0;
#pragma unroll
    for (int i = 0; i < 4; ++i) d[(ty + i * 8) * (size_t)R + tx] = f2bf(tile[tx][ty + i * 8]);
}

// ---------- mask bit-pack: mask[b][q][k] int32 -> mask64[b][kt][q] uint64 ----------
__global__ __launch_bounds__(256) void k_packmask(const int* __restrict__ mask,
                                                  unsigned long long* __restrict__ mask64) {
    int bid = blockIdx.x;            // b*16384 + kt*512 + q4
    int q4 = bid & 511, kt = (bid >> 9) & 31, b = bid >> 14;
    int wave = threadIdx.x >> 6, lane = threadIdx.x & 63;
    int q = q4 * 4 + wave;
    int m = mask[((size_t)(b * 2048 + q)) * 2048 + kt * 64 + lane];
    unsigned long long bal = __ballot(m != 0);
    if (lane == 0) mask64[((size_t)(b * 32 + kt)) * 2048 + q] = bal;
}

// ---------- q/k projections, 128-row tiles ----------
__global__ __launch_bounds__(256) void k_gemm_qk(
    const unsigned short* __restrict__ qb, const unsigned short* __restrict__ kb,
    const unsigned short* __restrict__ wqt, const unsigned short* __restrict__ wkt,
    unsigned short* __restrict__ qh, unsigned short* __restrict__ kh) {
    int tile = blockIdx.x;   // 0..15 -> 128 rows
    int hb = blockIdx.y, z = blockIdx.z;
    int h = hb >> 1, b = hb & 1;
    const unsigned short* X = z == 0 ? qb : kb;
    const unsigned short* W = (z == 0 ? wqt : wkt) + (size_t)h * 65536;
    unsigned short* O = (z == 0 ? qh : kh) + ((size_t)hb * 2048 + tile * 128) * 64;
    int wave = threadIdx.x >> 6, lane = threadIdx.x & 63;
    int l15 = lane & 15, quad = lane >> 4;
    const unsigned short* A0 =
        X + ((size_t)(b * 2048 + tile * 128 + wave * 32 + l15)) * 1024 + quad * 8;
    const unsigned short* A1 = A0 + 16 * 1024;
    const unsigned short* Bp = W + l15 * 1024 + quad * 8;
    f32x4 acc[2][4] = {};
    for (int k0 = 0; k0 < 1024; k0 += 32) {
        bf16x8 a0 = *(const bf16x8*)(A0 + k0);
        bf16x8 a1 = *(const bf16x8*)(A1 + k0);
#pragma unroll
        for (int t = 0; t < 4; ++t) {
            bf16x8 bf = *(const bf16x8*)(Bp + (size_t)t * 16 * 1024 + k0);
            acc[0][t] = MFMA16(a0, bf, acc[0][t]);
            acc[1][t] = MFMA16(a1, bf, acc[1][t]);
        }
    }
#pragma unroll
    for (int s = 0; s < 2; ++s)
#pragma unroll
        for (int t = 0; t < 4; ++t)
#pragma unroll
            for (int r = 0; r < 4; ++r)
                O[(size_t)(wave * 32 + s * 16 + quad * 4 + r) * 64 + t * 16 + l15] =
                    f2bf(acc[s][t][r]);
}

// ---------- v projection -> vt[hb][e][l] ----------
__global__ __launch_bounds__(256) void k_gemm_v(
    const unsigned short* __restrict__ vb, const unsigned short* __restrict__ wvt,
    unsigned short* __restrict__ vt) {
    int tile = blockIdx.x, hb = blockIdx.y;
    int h = hb >> 1, b = hb & 1;
    int wave = threadIdx.x >> 6, lane = threadIdx.x & 63;
    int l15 = lane & 15, quad = lane >> 4;
    const unsigned short* A =
        wvt + (size_t)h * 65536 + (wave * 16 + l15) * 1024 + quad * 8;   // rows = e
    const unsigned short* Bp =
        vb + ((size_t)(b * 2048 + tile * 64 + l15)) * 1024 + quad * 8;   // n-rows = l
    unsigned short* outp = vt + (size_t)hb * 131072 + tile * 64;
    f32x4 acc[4] = {};
    for (int k0 = 0; k0 < 1024; k0 += 32) {
        bf16x8 af = *(const bf16x8*)(A + k0);
#pragma unroll
        for (int t = 0; t < 4; ++t) {
            bf16x8 bf = *(const bf16x8*)(Bp + (size_t)t * 16 * 1024 + k0);
            acc[t] = MFMA16(af, bf, acc[t]);
        }
    }
#pragma unroll
    for (int t = 0; t < 4; ++t)
#pragma unroll
        for (int r = 0; r < 4; ++r)
            outp[(size_t)(wave * 16 + quad * 4 + r) * 2048 + t * 16 + l15] =
                f2bf(acc[t][r]);
}

// ---------- flash attention, S^T scheme + in-block K-split ----------
// grid (32 qtile, 32 hb), block 512 = 8 waves: w&3 -> 16-row group, w>>2 -> K half
__global__ __launch_bounds__(512, 6) void k_attn(
    const unsigned short* __restrict__ qh, const unsigned short* __restrict__ kh,
    const unsigned short* __restrict__ vt, const unsigned long long* __restrict__ mask64,
    unsigned short* __restrict__ ao) {
    int qt = blockIdx.x, hb = blockIdx.y;
    int h = hb >> 1, b = hb & 1;
    int tid = threadIdx.x;
    int wave = tid >> 6, lane = tid & 63;
    int w4 = wave & 3, khalf = wave >> 2;
    int l15 = lane & 15, quad = lane >> 4;

    __shared__ __align__(16) unsigned short Pbuf[8][16][72];
    __shared__ __align__(16) float Obuf[4][64][20];
    __shared__ float Mbuf[4][16], Lbuf[4][16];

    int qrow0 = qt * 64 + w4 * 16;
    const unsigned short* Qb = qh + ((size_t)(hb * 2048 + qrow0 + l15)) * 64 + quad * 8;
    bf16x8 qf0 = *(const bf16x8*)Qb;
    bf16x8 qf1 = *(const bf16x8*)(Qb + 32);

    const unsigned short* Kb = kh + (size_t)hb * 131072 + l15 * 64 + quad * 8;
    const unsigned short* Vb = vt + (size_t)hb * 131072 + l15 * 2048 + quad * 8;
    const unsigned long long* Mb = mask64 + (size_t)(b * 32) * 2048 + qrow0 + l15;

    const float cs = 0.18033688011112042f;  // log2(e)/8
    float m_r = -1e30f, l_r = 0.f;
    f32x4 o[4] = {};

    for (int kt = khalf * 16; kt < khalf * 16 + 16; ++kt) {
        // ---- S^T tile: MFMA(A=K rows, B=Q rows): lane = (qrow=l15, kcols quad*4+r) ----
        f32x4 st[4] = {};
        const unsigned short* kp = Kb + (size_t)kt * 4096;
#pragma unroll
        for (int t = 0; t < 4; ++t) {
            bf16x8 kf0 = *(const bf16x8*)(kp + t * 1024);
            bf16x8 kf1 = *(const bf16x8*)(kp + t * 1024 + 32);
            st[t] = MFMA16(kf0, qf0, st[t]);
            st[t] = MFMA16(kf1, qf1, st[t]);
        }
        // ---- mask: one packed 64-bit word per (qrow, kt) ----
        unsigned long long mw = Mb[(size_t)kt * 2048];
        unsigned int w0 = (unsigned int)(mw >> (quad * 4));
        unsigned int w1 = (unsigned int)(mw >> (32 + quad * 4));
#pragma unroll
        for (int r = 0; r < 4; ++r) {
            st[0][r] = ((w0 >> r) & 1u) ? -3e30f : st[0][r];
            st[1][r] = ((w0 >> (16 + r)) & 1u) ? -3e30f : st[1][r];
            st[2][r] = ((w1 >> r) & 1u) ? -3e30f : st[2][r];
            st[3][r] = ((w1 >> (16 + r)) & 1u) ? -3e30f : st[3][r];
        }
        // ---- row max (in-lane tree + 2 shfl across quads) ----
        float mx;
        {
            f32x4 m01, m23;
#pragma unroll
            for (int r = 0; r < 4; ++r) {
                m01[r] = fmaxf(st[0][r], st[1][r]);
                m23[r] = fmaxf(st[2][r], st[3][r]);
            }
            float a = fmaxf(fmaxf(m01[0], m23[0]), fmaxf(m01[1], m23[1]));
            float c = fmaxf(fmaxf(m01[2], m23[2]), fmaxf(m01[3], m23[3]));
            mx = fmaxf(a, c);
        }
        mx = fmaxf(mx, __shfl_xor(mx, 16, 64));
        mx = fmaxf(mx, __shfl_xor(mx, 32, 64));
        float mnew = fmaxf(m_r, mx);
        float alpha = __builtin_amdgcn_exp2f((m_r - mnew) * cs);
        m_r = mnew;
        // ---- p = exp2((s-m)*cs), accumulate sum, pack to bf16, LDS ----
        float ps = 0.f;
#pragma unroll
        for (int t = 0; t < 4; ++t) {
            float p0 = __builtin_amdgcn_exp2f((st[t][0] - mnew) * cs);
            float p1 = __builtin_amdgcn_exp2f((st[t][1] - mnew) * cs);
            float p2 = __builtin_amdgcn_exp2f((st[t][2] - mnew) * cs);
            float p3 = __builtin_amdgcn_exp2f((st[t][3] - mnew) * cs);
            ps += (p0 + p1) + (p2 + p3);
            uint2 pk;
            pk.x = (__float_as_uint(p1) & 0xffff0000u) | (__float_as_uint(p0) >> 16);
            pk.y = (__float_as_uint(p3) & 0xffff0000u) | (__float_as_uint(p2) >> 16);
            *(uint2*)&Pbuf[wave][l15][t * 16 + quad * 4] = pk;
        }
        ps += __shfl_xor(ps, 16, 64);
        ps += __shfl_xor(ps, 32, 64);
        l_r = l_r * alpha + ps;
        // ---- rescale O by alpha (redistribute qrow alpha into C-layout rows) ----
        f32x4 a4;
#pragma unroll
        for (int r = 0; r < 4; ++r) a4[r] = __shfl(alpha, quad * 4 + r, 16);
#pragma unroll
        for (int t = 0; t < 4; ++t)
#pragma unroll
            for (int r = 0; r < 4; ++r) o[t][r] *= a4[r];
        // ---- O += P @ V ----
#pragma unroll
        for (int kc = 0; kc < 2; ++kc) {
            bf16x8 pf = *(const bf16x8*)&Pbuf[wave][l15][kc * 32 + quad * 8];
            const unsigned short* vp = Vb + (size_t)kt * 64 + kc * 32;
#pragma unroll
            for (int t = 0; t < 4; ++t) {
                bf16x8 vf = *(const bf16x8*)(vp + (size_t)t * 32768);
                o[t] = MFMA16(pf, vf, o[t]);
            }
        }
    }
    // ---- merge K halves ----
    if (khalf == 1) {
#pragma unroll
        for (int t = 0; t < 4; ++t)
            *(f32x4*)&Obuf[w4][t * 16 + l15][quad * 4] = o[t];
        if (quad == 0) { Mbuf[w4][l15] = m_r; Lbuf[w4][l15] = l_r; }
    }
    __syncthreads();
    if (khalf == 0) {
        float m1 = Mbuf[w4][l15], l1 = Lbuf[w4][l15];
        float ms = fmaxf(m_r, m1);
        float c0 = __builtin_amdgcn_exp2f((m_r - ms) * cs);
        float c1 = __builtin_amdgcn_exp2f((m1 - ms) * cs);
        float inv = 1.0f / (l_r * c0 + l1 * c1);
        f32x4 c0r, c1r, ivr;
#pragma unroll
        for (int r = 0; r < 4; ++r) {
            c0r[r] = __shfl(c0, quad * 4 + r, 16);
            c1r[r] = __shfl(c1, quad * 4 + r, 16);
            ivr[r] = __shfl(inv, quad * 4 + r, 16);
        }
#pragma unroll
        for (int t = 0; t < 4; ++t) {
            f32x4 o1 = *(const f32x4*)&Obuf[w4][t * 16 + l15][quad * 4];
#pragma unroll
            for (int r = 0; r < 4; ++r) {
                float val = (o[t][r] * c0r[r] + o1[r] * c1r[r]) * ivr[r];
                int mrow = qt * 64 + w4 * 16 + quad * 4 + r;
                ao[((size_t)(b * 2048 + mrow)) * 1024 + h * 64 + t * 16 + l15] = f2bf(val);
            }
        }
    }
}

// ---------- output projection + bias + residual, 128-row tiles ----------
__global__ __launch_bounds__(256) void k_gemm_out(
    const unsigned short* __restrict__ ao, const unsigned short* __restrict__ wot,
    const float* __restrict__ bo, const float* __restrict__ resid,
    float* __restrict__ xbuf) {
    int mt = blockIdx.x, nt = blockIdx.y;
    int wave = threadIdx.x >> 6, lane = threadIdx.x & 63;
    int l15 = lane & 15, quad = lane >> 4;
    const unsigned short* A0 =
        ao + ((size_t)(mt * 128 + wave * 32 + l15)) * 1024 + quad * 8;
    const unsigned short* A1 = A0 + 16 * 1024;
    const unsigned short* Bp = wot + ((size_t)(nt * 64 + l15)) * 1024 + quad * 8;
    f32x4 acc[2][4] = {};
    for (int k0 = 0; k0 < 1024; k0 += 32) {
        bf16x8 a0 = *(const bf16x8*)(A0 + k0);
        bf16x8 a1 = *(const bf16x8*)(A1 + k0);
#pragma unroll
        for (int t = 0; t < 4; ++t) {
            bf16x8 bf = *(const bf16x8*)(Bp + (size_t)t * 16 * 1024 + k0);
            acc[0][t] = MFMA16(a0, bf, acc[0][t]);
            acc[1][t] = MFMA16(a1, bf, acc[1][t]);
        }
    }
#pragma unroll
    for (int s = 0; s < 2; ++s)
#pragma unroll
        for (int t = 0; t < 4; ++t) {
            int n = nt * 64 + t * 16 + l15;
            float bov = bo[n];
#pragma unroll
            for (int r = 0; r < 4; ++r) {
                int m = mt * 128 + wave * 32 + s * 16 + quad * 4 + r;
                xbuf[(size_t)m * 1024 + n] = acc[s][t][r] + bov + resid[(size_t)m * 1024 + n];
            }
        }
}

// ---------- layernorm (torch: std ddof=1, eps on std) ----------
__global__ __launch_bounds__(256) void k_ln(const float* __restrict__ x,
                                            const float* __restrict__ gamma,
                                            const float* __restrict__ beta,
                                            float* __restrict__ out) {
    int row = blockIdx.x;
    const float* xr = x + (size_t)row * 1024;
    float4 v = ((const float4*)xr)[threadIdx.x];
    float s = v.x + v.y + v.z + v.w;
    float ss = v.x * v.x + v.y * v.y + v.z * v.z + v.w * v.w;
#pragma unroll
    for (int off = 32; off; off >>= 1) {
        s += __shfl_down(s, off, 64);
        ss += __shfl_down(ss, off, 64);
    }
    __shared__ float sb[8];
    int wave = threadIdx.x >> 6, lane = threadIdx.x & 63;
    if (lane == 0) { sb[wave] = s; sb[4 + wave] = ss; }
    __syncthreads();
    s = sb[0] + sb[1] + sb[2] + sb[3];
    ss = sb[4] + sb[5] + sb[6] + sb[7];
    float mean = s * (1.0f / 1024.0f);
    float var = fmaxf((ss - 1024.0f * mean * mean) * (1.0f / 1023.0f), 0.f);
    float inv = 1.0f / (sqrtf(var) + 1e-3f);
    float4 g = ((const float4*)gamma)[threadIdx.x];
    float4 bt = ((const float4*)beta)[threadIdx.x];
    float4 o;
    o.x = (v.x - mean) * inv * g.x + bt.x;
    o.y = (v.y - mean) * inv * g.y + bt.y;
    o.z = (v.z - mean) * inv * g.z + bt.z;
    o.w = (v.w - mean) * inv * g.w + bt.w;
    ((float4*)(out + (size_t)row * 1024))[threadIdx.x] = o;
}

// ---------- launch ----------
extern "C" void kernel_launch(void* const* d_in, const int* in_sizes, int n_in,
                              void* d_out, int out_size, void* d_ws, size_t ws_size,
                              hipStream_t stream) {
    const float* v_in  = (const float*)d_in[0];
    const float* k_in  = (const float*)d_in[1];
    const float* q_in  = (const float*)d_in[2];
    const int*   mask  = (const int*)d_in[3];
    const float* w_q   = (const float*)d_in[4];
    const float* w_k   = (const float*)d_in[5];
    const float* w_v   = (const float*)d_in[6];
    const float* w_o   = (const float*)d_in[7];
    const float* b_o   = (const float*)d_in[8];
    const float* gamma = (const float*)d_in[9];
    const float* beta  = (const float*)d_in[10];
    float* out = (float*)d_out;

    char* ws = (char*)d_ws;
    const size_t MB = 1ull << 20;
    unsigned short* qb  = (unsigned short*)(ws + 0 * MB);
    unsigned short* kb  = (unsigned short*)(ws + 8 * MB);
    unsigned short* vb  = (unsigned short*)(ws + 16 * MB);
    unsigned short* wqt = (unsigned short*)(ws + 24 * MB);
    unsigned short* wkt = (unsigned short*)(ws + 26 * MB);
    unsigned short* wvt = (unsigned short*)(ws + 28 * MB);
    unsigned short* wot = (unsigned short*)(ws + 30 * MB);
    unsigned short* qh  = (unsigned short*)(ws + 32 * MB);
    unsigned short* kh  = (unsigned short*)(ws + 40 * MB);
    unsigned short* vt  = (unsigned short*)(ws + 48 * MB);
    unsigned short* ao  = (unsigned short*)(ws + 56 * MB);
    unsigned long long* mask64 = (unsigned long long*)(ws + 64 * MB);  // dead before xb written
    float*          xb  = (float*)(ws + 64 * MB);

    k_cvt3<<<dim3(4096, 3), dim3(256), 0, stream>>>(q_in, k_in, v_in, qb, kb, vb);
    k_tcvt<<<dim3(32, 2, 16), dim3(256), 0, stream>>>(w_q, wqt, 1024, 64);
    k_tcvt<<<dim3(32, 2, 16), dim3(256), 0, stream>>>(w_k, wkt, 1024, 64);
    k_tcvt<<<dim3(32, 2, 16), dim3(256), 0, stream>>>(w_v, wvt, 1024, 64);
    k_tcvt<<<dim3(32, 32, 1), dim3(256), 0, stream>>>(w_o, wot, 1024, 1024);
    k_packmask<<<dim3(32768), dim3(256), 0, stream>>>(mask, mask64);
    k_gemm_qk<<<dim3(16, 32, 2), dim3(256), 0, stream>>>(qb, kb, wqt, wkt, qh, kh);
    k_gemm_v<<<dim3(32, 32), dim3(256), 0, stream>>>(vb, wvt, vt);
    k_attn<<<dim3(32, 32), dim3(512), 0, stream>>>(qh, kh, vt, mask64, ao);
    k_gemm_out<<<dim3(32, 16), dim3(256), 0, stream>>>(ao, wot, b_o, k_in, xb);
    k_ln<<<dim3(4096), dim3(256), 0, stream>>>(xb, gamma, beta, out);
}

// Round 3
// 343.648 us; speedup vs baseline: 1.9897x; 1.8130x over previous
//
#include <hip/hip_runtime.h>
#include <math.h>

// ---------- types ----------
typedef __bf16 bf16_t;
typedef bf16_t bf16x8 __attribute__((ext_vector_type(8)));
typedef float  f32x4  __attribute__((ext_vector_type(4)));
typedef unsigned short u16;
typedef u16 ushortx4 __attribute__((ext_vector_type(4)));
typedef unsigned long long u64;

#define MFMA16(a, b, c) __builtin_amdgcn_mfma_f32_16x16x32_bf16((a), (b), (c), 0, 0, 0)

__device__ __forceinline__ u16 f2bf(float f) {
    unsigned int u = __float_as_uint(f);
    u = (u + 0x7fffu + ((u >> 16) & 1u)) >> 16;
    return (u16)u;
}

// async global->LDS, 16B per lane; lds dest = wave-uniform base + lane*16
__device__ __forceinline__ void gld16(const u16* g, u16* l) {
    __builtin_amdgcn_global_load_lds(
        (const __attribute__((address_space(1))) void*)g,
        (__attribute__((address_space(3))) void*)l, 16, 0, 0);
}

// B=2, L=2048, D_MODEL=1024, H=16, DH=64, HB=32
// ws layout (bytes):
//  qb 0..8M, kb 8..16M, vb 16..24M   (bf16 [b*2048+l][1024])
//  wqt 24M, wkt 26M, wvt 28M         (bf16 [h][e][d] -> flat [1024][1024])
//  wot 30M                           (bf16 [n][k])
//  qh 32M, kh 40M                    (bf16 [hb][l][64])
//  vt 48M                            (bf16 [hb][e][l])
//  ao 56M                            (bf16 [b*2048+l][1024])
//  mask64 64M (1MB, dead after attn) then xb 64M..80M (fp32) overwrites it

// ---------- fused fp32 -> bf16 for q,k,v ----------
__global__ __launch_bounds__(256) void k_cvt3(const float* __restrict__ q,
                                              const float* __restrict__ k,
                                              const float* __restrict__ v,
                                              u16* __restrict__ qb,
                                              u16* __restrict__ kb,
                                              u16* __restrict__ vb) {
    int i = blockIdx.x * 256 + threadIdx.x;
    int sel = blockIdx.y;
    const float* src = sel == 0 ? q : (sel == 1 ? k : v);
    u16* dst = sel == 0 ? qb : (sel == 1 ? kb : vb);
    float4 val = ((const float4*)src)[i];
    ushortx4 r;
    r[0] = f2bf(val.x); r[1] = f2bf(val.y); r[2] = f2bf(val.z); r[3] = f2bf(val.w);
    ((ushortx4*)dst)[i] = r;
}

// ---------- transpose + convert: src [H][R][C] fp32 -> dst [H][C][R] bf16 ----------
__global__ __launch_bounds__(256) void k_tcvt(const float* __restrict__ src,
                                              u16* __restrict__ dst, int R, int C) {
    __shared__ float tile[32][33];
    int h = blockIdx.z;
    int r0 = blockIdx.x * 32, c0 = blockIdx.y * 32;
    int tx = threadIdx.x & 31, ty = threadIdx.x >> 5;
    const float* s = src + ((size_t)h * R + r0) * C + c0;
#pragma unroll
    for (int i = 0; i < 4; ++i) tile[ty + i * 8][tx] = s[(ty + i * 8) * (size_t)C + tx];
    __syncthreads();
    u16* d = dst + ((size_t)h * C + c0) * R + r0;
#pragma unroll
    for (int i = 0; i < 4; ++i) d[(ty + i * 8) * (size_t)R + tx] = f2bf(tile[tx][ty + i * 8]);
}

// ---------- mask bit-pack: mask[b][q][k] int32 -> mask64[b][kt][q] uint64 ----------
__global__ __launch_bounds__(256) void k_packmask(const int* __restrict__ mask,
                                                  u64* __restrict__ mask64) {
    int bid = blockIdx.x;  // b*16384 + kt*512 + q4
    int q4 = bid & 511, kt = (bid >> 9) & 31, b = bid >> 14;
    int wave = threadIdx.x >> 6, lane = threadIdx.x & 63;
    int q = q4 * 4 + wave;
    int m = mask[((size_t)(b * 2048 + q)) * 2048 + kt * 64 + lane];
    u64 bal = __ballot(m != 0);
    if (lane == 0) mask64[((size_t)(b * 32 + kt)) * 2048 + q] = bal;
}

// ---------- shared GEMM core: 128x128 tile, BK=32, NT (both K-major, K=1024) ----------
// 256 threads = 4 waves in 2x2; LDS tiles stored in MFMA-frag chunk order:
// chunk t (0..7) = rows t*16..+16 x k 0..32, lane-sequential 16B units.
#define GEMM_CORE(Ablk, Bblk, ACC)                                                   \
    __shared__ __align__(16) u16 As[2][4096], Bs[2][4096];                           \
    int c0 = wave * 2;                                                               \
    const u16* Ag0 = Ablk + (size_t)(c0 * 16 + l15) * 1024 + quad * 8;               \
    const u16* Ag1 = Ablk + (size_t)((c0 + 1) * 16 + l15) * 1024 + quad * 8;         \
    const u16* Bg0 = Bblk + (size_t)(c0 * 16 + l15) * 1024 + quad * 8;               \
    const u16* Bg1 = Bblk + (size_t)((c0 + 1) * 16 + l15) * 1024 + quad * 8;         \
    gld16(Ag0, &As[0][c0 * 512]); gld16(Ag1, &As[0][(c0 + 1) * 512]);                \
    gld16(Bg0, &Bs[0][c0 * 512]); gld16(Bg1, &Bs[0][(c0 + 1) * 512]);                \
    __syncthreads();                                                                 \
    int buf = 0;                                                                     \
    for (int ks = 0; ks < 32; ++ks) {                                                \
        if (ks < 31) {                                                               \
            int k0 = (ks + 1) * 32;                                                  \
            gld16(Ag0 + k0, &As[buf ^ 1][c0 * 512]);                                 \
            gld16(Ag1 + k0, &As[buf ^ 1][(c0 + 1) * 512]);                           \
            gld16(Bg0 + k0, &Bs[buf ^ 1][c0 * 512]);                                 \
            gld16(Bg1 + k0, &Bs[buf ^ 1][(c0 + 1) * 512]);                           \
        }                                                                            \
        bf16x8 af[4], bfr[4];                                                        \
        _Pragma("unroll")                                                            \
        for (int i = 0; i < 4; ++i)                                                  \
            af[i] = *(const bf16x8*)&As[buf][(wy * 4 + i) * 512 + lane * 8];         \
        _Pragma("unroll")                                                            \
        for (int j = 0; j < 4; ++j)                                                  \
            bfr[j] = *(const bf16x8*)&Bs[buf][(wx * 4 + j) * 512 + lane * 8];        \
        _Pragma("unroll")                                                            \
        for (int i = 0; i < 4; ++i)                                                  \
            _Pragma("unroll")                                                        \
            for (int j = 0; j < 4; ++j) ACC[i][j] = MFMA16(af[i], bfr[j], ACC[i][j]); \
        __syncthreads();                                                             \
        buf ^= 1;                                                                    \
    }

// ---------- fused q/k/v projections ----------
// z=0: qh = qb@Wq  (M=4096 rows x, N=1024 e_g), z=1: kh, z=2: vt = Wv@vb^T (M=1024 e_g, N=4096 l_g)
__global__ __launch_bounds__(256) void k_proj(
    const u16* __restrict__ qb, const u16* __restrict__ kb, const u16* __restrict__ vb,
    const u16* __restrict__ wqt, const u16* __restrict__ wkt, const u16* __restrict__ wvt,
    u16* __restrict__ oq, u16* __restrict__ okh, u16* __restrict__ ovt) {
    int z = blockIdx.y, gx = blockIdx.x;
    int bm, bn;
    const u16 *A, *B;
    if (z == 0)      { bm = gx >> 3; bn = gx & 7; A = qb; B = wqt; }
    else if (z == 1) { bm = gx >> 3; bn = gx & 7; A = kb; B = wkt; }
    else             { bm = gx & 7; bn = gx >> 3; A = wvt; B = vb; }
    A += (size_t)bm * 128 * 1024;
    B += (size_t)bn * 128 * 1024;
    int tid = threadIdx.x, wave = tid >> 6, lane = tid & 63;
    int wy = wave >> 1, wx = wave & 1, l15 = lane & 15, quad = lane >> 4;
    f32x4 acc[4][4] = {};
    GEMM_CORE(A, B, acc)
    if (z < 2) {
        u16* O = z ? okh : oq;
#pragma unroll
        for (int i = 0; i < 4; ++i) {
            int m = bm * 128 + wy * 64 + i * 16 + quad * 4;
            int bb = m >> 11, l = m & 2047;
#pragma unroll
            for (int j = 0; j < 4; ++j) {
                int n = bn * 128 + wx * 64 + j * 16 + l15;
                int hh = n >> 6, e = n & 63;
                u16* dst = O + ((size_t)((hh * 2 + bb) * 2048 + l)) * 64 + e;
#pragma unroll
                for (int r = 0; r < 4; ++r) dst[(size_t)r * 64] = f2bf(acc[i][j][r]);
            }
        }
    } else {
#pragma unroll
        for (int i = 0; i < 4; ++i) {
            int m = bm * 128 + wy * 64 + i * 16 + quad * 4;  // e_g
            int hh = m >> 6, e = m & 63;
#pragma unroll
            for (int j = 0; j < 4; ++j) {
                int n = bn * 128 + wx * 64 + j * 16 + l15;   // l_g
                int bb = n >> 11, l = n & 2047;
                u16* dst = ovt + (size_t)(hh * 2 + bb) * 131072 + (size_t)e * 2048 + l;
#pragma unroll
                for (int r = 0; r < 4; ++r) dst[(size_t)r * 2048] = f2bf(acc[i][j][r]);
            }
        }
    }
}

// ---------- output projection + bias + residual ----------
__global__ __launch_bounds__(256) void k_out(
    const u16* __restrict__ ao, const u16* __restrict__ wot,
    const float* __restrict__ bo, const float* __restrict__ resid,
    float* __restrict__ xb) {
    int gx = blockIdx.x, bm = gx >> 3, bn = gx & 7;
    const u16* A = ao + (size_t)bm * 128 * 1024;
    const u16* B = wot + (size_t)bn * 128 * 1024;
    int tid = threadIdx.x, wave = tid >> 6, lane = tid & 63;
    int wy = wave >> 1, wx = wave & 1, l15 = lane & 15, quad = lane >> 4;
    f32x4 acc[4][4] = {};
    GEMM_CORE(A, B, acc)
#pragma unroll
    for (int j = 0; j < 4; ++j) {
        int n = bn * 128 + wx * 64 + j * 16 + l15;
        float bov = bo[n];
#pragma unroll
        for (int i = 0; i < 4; ++i) {
            int m0 = bm * 128 + wy * 64 + i * 16 + quad * 4;
#pragma unroll
            for (int r = 0; r < 4; ++r) {
                size_t idx = (size_t)(m0 + r) * 1024 + n;
                xb[idx] = acc[i][j][r] + bov + resid[idx];
            }
        }
    }
}

// ---------- flash attention: 128 Q-rows/block, LDS-staged K/V, double-buffered ----------
// grid (16 qt, 32 hb), block 512 = 8 waves, wave w owns Q rows qt*128+w*16..+16
__global__ __launch_bounds__(512) void k_attn(
    const u16* __restrict__ qh, const u16* __restrict__ kh,
    const u16* __restrict__ vt, const u64* __restrict__ mask64,
    u16* __restrict__ ao) {
    int qt = blockIdx.x, hb = blockIdx.y;
    int h = hb >> 1, b = hb & 1;
    int tid = threadIdx.x, wave = tid >> 6, lane = tid & 63;
    int l15 = lane & 15, quad = lane >> 4;

    __shared__ __align__(16) u16 Ks[2][4096], Vs[2][4096];
    __shared__ __align__(16) u16 Pb[8][16][72];

    int qrow0 = qt * 128 + wave * 16;
    const u16* Qp = qh + ((size_t)(hb * 2048) + qrow0 + l15) * 64 + quad * 8;
    bf16x8 qf0 = *(const bf16x8*)Qp;
    bf16x8 qf1 = *(const bf16x8*)(Qp + 32);

    // staging: wave stages K chunk (tK=w>>1, hK=w&1) and V chunk (same indices) -> chunk id = wave
    int tK = wave >> 1, hK = wave & 1;
    const u16* Kg = kh + (size_t)hb * 131072 + (size_t)(tK * 16 + l15) * 64 + hK * 32 + quad * 8;
    const u16* Vg = vt + (size_t)hb * 131072 + (size_t)(tK * 16 + l15) * 2048 + hK * 32 + quad * 8;
    const u16* Vbq = 0; (void)Vbq;
    const u64* Mp = mask64 + (size_t)b * 65536 + qrow0 + l15;

    const float cs = 0.18033688011112042f;  // log2(e)/8
    float m_r = -1e30f, l_r = 0.f;
    f32x4 o[4] = {};

    gld16(Kg, &Ks[0][wave * 512]);
    gld16(Vg, &Vs[0][wave * 512]);
    __syncthreads();
    int buf = 0;
    for (int kt = 0; kt < 32; ++kt) {
        if (kt < 31) {
            gld16(Kg + (size_t)(kt + 1) * 4096, &Ks[buf ^ 1][wave * 512]);
            gld16(Vg + (size_t)(kt + 1) * 64, &Vs[buf ^ 1][wave * 512]);
        }
        u64 mw = Mp[(size_t)kt * 2048];
        // ---- S^T: lane = (qrow=l15, kcol=quad*4+r), t over 4 kcol-tiles ----
        f32x4 st[4] = {};
#pragma unroll
        for (int t = 0; t < 4; ++t) {
            bf16x8 k0 = *(const bf16x8*)&Ks[buf][(t * 2 + 0) * 512 + lane * 8];
            bf16x8 k1 = *(const bf16x8*)&Ks[buf][(t * 2 + 1) * 512 + lane * 8];
            st[t] = MFMA16(k0, qf0, st[t]);
            st[t] = MFMA16(k1, qf1, st[t]);
        }
        // ---- mask ----
        unsigned int w0 = (unsigned int)(mw >> (quad * 4));
        unsigned int w1 = (unsigned int)(mw >> (32 + quad * 4));
#pragma unroll
        for (int r = 0; r < 4; ++r) {
            st[0][r] = ((w0 >> r) & 1u) ? -3e30f : st[0][r];
            st[1][r] = ((w0 >> (16 + r)) & 1u) ? -3e30f : st[1][r];
            st[2][r] = ((w1 >> r) & 1u) ? -3e30f : st[2][r];
            st[3][r] = ((w1 >> (16 + r)) & 1u) ? -3e30f : st[3][r];
        }
        // ---- row max ----
        float mx;
        {
            float a = fmaxf(fmaxf(st[0][0], st[1][0]), fmaxf(st[2][0], st[3][0]));
            float c = fmaxf(fmaxf(st[0][1], st[1][1]), fmaxf(st[2][1], st[3][1]));
            float d = fmaxf(fmaxf(st[0][2], st[1][2]), fmaxf(st[2][2], st[3][2]));
            float e = fmaxf(fmaxf(st[0][3], st[1][3]), fmaxf(st[2][3], st[3][3]));
            mx = fmaxf(fmaxf(a, c), fmaxf(d, e));
        }
        mx = fmaxf(mx, __shfl_xor(mx, 16, 64));
        mx = fmaxf(mx, __shfl_xor(mx, 32, 64));
        float mnew = fmaxf(m_r, mx);
        float alpha = __builtin_amdgcn_exp2f((m_r - mnew) * cs);
        m_r = mnew;
        // ---- p = exp2((s-m)*cs), sum, pack bf16 -> Pb ----
        float ps = 0.f;
#pragma unroll
        for (int t = 0; t < 4; ++t) {
            float p0 = __builtin_amdgcn_exp2f((st[t][0] - mnew) * cs);
            float p1 = __builtin_amdgcn_exp2f((st[t][1] - mnew) * cs);
            float p2 = __builtin_amdgcn_exp2f((st[t][2] - mnew) * cs);
            float p3 = __builtin_amdgcn_exp2f((st[t][3] - mnew) * cs);
            ps += (p0 + p1) + (p2 + p3);
            uint2 pk;
            pk.x = (__float_as_uint(p1) & 0xffff0000u) | (__float_as_uint(p0) >> 16);
            pk.y = (__float_as_uint(p3) & 0xffff0000u) | (__float_as_uint(p2) >> 16);
            *(uint2*)&Pb[wave][l15][t * 16 + quad * 4] = pk;
        }
        ps += __shfl_xor(ps, 16, 64);
        ps += __shfl_xor(ps, 32, 64);
        l_r = l_r * alpha + ps;
        // ---- rescale O ----
        f32x4 a4;
#pragma unroll
        for (int r = 0; r < 4; ++r) a4[r] = __shfl(alpha, quad * 4 + r, 16);
#pragma unroll
        for (int t = 0; t < 4; ++t)
#pragma unroll
            for (int r = 0; r < 4; ++r) o[t][r] *= a4[r];
        // ---- O += P @ V ----
#pragma unroll
        for (int kc = 0; kc < 2; ++kc) {
            bf16x8 pf = *(const bf16x8*)&Pb[wave][l15][kc * 32 + quad * 8];
#pragma unroll
            for (int t = 0; t < 4; ++t) {
                bf16x8 vf = *(const bf16x8*)&Vs[buf][(t * 2 + kc) * 512 + lane * 8];
                o[t] = MFMA16(pf, vf, o[t]);
            }
        }
        __syncthreads();
        buf ^= 1;
    }
    // ---- normalize + store ----
    float inv = 1.0f / l_r;
    f32x4 ivr;
#pragma unroll
    for (int r = 0; r < 4; ++r) ivr[r] = __shfl(inv, quad * 4 + r, 16);
#pragma unroll
    for (int t = 0; t < 4; ++t)
#pragma unroll
        for (int r = 0; r < 4; ++r) {
            int mrow = qrow0 + quad * 4 + r;
            ao[((size_t)(b * 2048 + mrow)) * 1024 + h * 64 + t * 16 + l15] =
                f2bf(o[t][r] * ivr[r]);
        }
}

// ---------- layernorm (torch: std ddof=1, eps on std) ----------
__global__ __launch_bounds__(256) void k_ln(const float* __restrict__ x,
                                            const float* __restrict__ gamma,
                                            const float* __restrict__ beta,
                                            float* __restrict__ out) {
    int row = blockIdx.x;
    const float* xr = x + (size_t)row * 1024;
    float4 v = ((const float4*)xr)[threadIdx.x];
    float s = v.x + v.y + v.z + v.w;
    float ss = v.x * v.x + v.y * v.y + v.z * v.z + v.w * v.w;
#pragma unroll
    for (int off = 32; off; off >>= 1) {
        s += __shfl_down(s, off, 64);
        ss += __shfl_down(ss, off, 64);
    }
    __shared__ float sb[8];
    int wave = threadIdx.x >> 6, lane = threadIdx.x & 63;
    if (lane == 0) { sb[wave] = s; sb[4 + wave] = ss; }
    __syncthreads();
    s = sb[0] + sb[1] + sb[2] + sb[3];
    ss = sb[4] + sb[5] + sb[6] + sb[7];
    float mean = s * (1.0f / 1024.0f);
    float var = fmaxf((ss - 1024.0f * mean * mean) * (1.0f / 1023.0f), 0.f);
    float inv = 1.0f / (sqrtf(var) + 1e-3f);
    float4 g = ((const float4*)gamma)[threadIdx.x];
    float4 bt = ((const float4*)beta)[threadIdx.x];
    float4 o;
    o.x = (v.x - mean) * inv * g.x + bt.x;
    o.y = (v.y - mean) * inv * g.y + bt.y;
    o.z = (v.z - mean) * inv * g.z + bt.z;
    o.w = (v.w - mean) * inv * g.w + bt.w;
    ((float4*)(out + (size_t)row * 1024))[threadIdx.x] = o;
}

// ---------- launch ----------
extern "C" void kernel_launch(void* const* d_in, const int* in_sizes, int n_in,
                              void* d_out, int out_size, void* d_ws, size_t ws_size,
                              hipStream_t stream) {
    const float* v_in  = (const float*)d_in[0];
    const float* k_in  = (const float*)d_in[1];
    const float* q_in  = (const float*)d_in[2];
    const int*   mask  = (const int*)d_in[3];
    const float* w_q   = (const float*)d_in[4];
    const float* w_k   = (const float*)d_in[5];
    const float* w_v   = (const float*)d_in[6];
    const float* w_o   = (const float*)d_in[7];
    const float* b_o   = (const float*)d_in[8];
    const float* gamma = (const float*)d_in[9];
    const float* beta  = (const float*)d_in[10];
    float* out = (float*)d_out;

    char* ws = (char*)d_ws;
    const size_t MB = 1ull << 20;
    u16* qb  = (u16*)(ws + 0 * MB);
    u16* kb  = (u16*)(ws + 8 * MB);
    u16* vb  = (u16*)(ws + 16 * MB);
    u16* wqt = (u16*)(ws + 24 * MB);
    u16* wkt = (u16*)(ws + 26 * MB);
    u16* wvt = (u16*)(ws + 28 * MB);
    u16* wot = (u16*)(ws + 30 * MB);
    u16* qh  = (u16*)(ws + 32 * MB);
    u16* kh  = (u16*)(ws + 40 * MB);
    u16* vt  = (u16*)(ws + 48 * MB);
    u16* ao  = (u16*)(ws + 56 * MB);
    u64* mask64 = (u64*)(ws + 64 * MB);  // dead before xb written
    float* xb = (float*)(ws + 64 * MB);

    k_cvt3<<<dim3(4096, 3), dim3(256), 0, stream>>>(q_in, k_in, v_in, qb, kb, vb);
    k_tcvt<<<dim3(32, 2, 16), dim3(256), 0, stream>>>(w_q, wqt, 1024, 64);
    k_tcvt<<<dim3(32, 2, 16), dim3(256), 0, stream>>>(w_k, wkt, 1024, 64);
    k_tcvt<<<dim3(32, 2, 16), dim3(256), 0, stream>>>(w_v, wvt, 1024, 64);
    k_tcvt<<<dim3(32, 32, 1), dim3(256), 0, stream>>>(w_o, wot, 1024, 1024);
    k_packmask<<<dim3(32768), dim3(256), 0, stream>>>(mask, mask64);
    k_proj<<<dim3(256, 3), dim3(256), 0, stream>>>(qb, kb, vb, wqt, wkt, wvt, qh, kh, vt);
    k_attn<<<dim3(16, 32), dim3(512), 0, stream>>>(qh, kh, vt, mask64, ao);
    k_out<<<dim3(256), dim3(256), 0, stream>>>(ao, wot, b_o, k_in, xb);
    k_ln<<<dim3(4096), dim3(256), 0, stream>>>(xb, gamma, beta, out);
}

// Round 4
// 303.188 us; speedup vs baseline: 2.2553x; 1.1334x over previous
//
#include <hip/hip_runtime.h>
#include <math.h>

// ---------- types ----------
typedef __bf16 bf16_t;
typedef bf16_t bf16x8 __attribute__((ext_vector_type(8)));
typedef float  f32x4  __attribute__((ext_vector_type(4)));
typedef unsigned short u16;
typedef u16 ushortx4 __attribute__((ext_vector_type(4)));
typedef unsigned long long u64;

#define MFMA16(a, b, c) __builtin_amdgcn_mfma_f32_16x16x32_bf16((a), (b), (c), 0, 0, 0)

__device__ __forceinline__ u16 f2bf(float f) {
    unsigned int u = __float_as_uint(f);
    u = (u + 0x7fffu + ((u >> 16) & 1u)) >> 16;
    return (u16)u;
}

// async global->LDS, 16B per lane; lds dest = wave-uniform base + lane*16
__device__ __forceinline__ void gld16(const u16* g, u16* l) {
    __builtin_amdgcn_global_load_lds(
        (const __attribute__((address_space(1))) void*)g,
        (__attribute__((address_space(3))) void*)l, 16, 0, 0);
}

// B=2, L=2048, D_MODEL=1024, H=16, DH=64, HB=32
// ws: qb 0..8M, kb 8..16M, vb 16..24M; wqt 24M wkt 26M wvt 28M wot 30M;
//     qh 32M (pre-scaled by log2e/8), kh 40M, vt 48M, ao 56M;
//     mask64 64M (dead before xb), xb 64M..80M fp32

// ---------- fused fp32 -> bf16 for q,k,v ----------
__global__ __launch_bounds__(256) void k_cvt3(const float* __restrict__ q,
                                              const float* __restrict__ k,
                                              const float* __restrict__ v,
                                              u16* __restrict__ qb,
                                              u16* __restrict__ kb,
                                              u16* __restrict__ vb) {
    int i = blockIdx.x * 256 + threadIdx.x;
    int sel = blockIdx.y;
    const float* src = sel == 0 ? q : (sel == 1 ? k : v);
    u16* dst = sel == 0 ? qb : (sel == 1 ? kb : vb);
    float4 val = ((const float4*)src)[i];
    ushortx4 r;
    r[0] = f2bf(val.x); r[1] = f2bf(val.y); r[2] = f2bf(val.z); r[3] = f2bf(val.w);
    ((ushortx4*)dst)[i] = r;
}

// ---------- transpose+convert the 3 qkv weights: [48 z][1024][64] -> [z][64][1024] ----------
__global__ __launch_bounds__(256) void k_tcvt3(const float* __restrict__ w_q,
                                               const float* __restrict__ w_k,
                                               const float* __restrict__ w_v,
                                               u16* __restrict__ wqt,
                                               u16* __restrict__ wkt,
                                               u16* __restrict__ wvt) {
    __shared__ float tile[32][33];
    int z = blockIdx.z, h = z & 15, sel = z >> 4;
    const float* src = (sel == 0 ? w_q : (sel == 1 ? w_k : w_v));
    u16* dst = (sel == 0 ? wqt : (sel == 1 ? wkt : wvt));
    int r0 = blockIdx.x * 32, c0 = blockIdx.y * 32;
    int tx = threadIdx.x & 31, ty = threadIdx.x >> 5;
    const float* s = src + ((size_t)h * 1024 + r0) * 64 + c0;
#pragma unroll
    for (int i = 0; i < 4; ++i) tile[ty + i * 8][tx] = s[(ty + i * 8) * 64 + tx];
    __syncthreads();
    u16* d = dst + ((size_t)h * 64 + c0) * 1024 + r0;
#pragma unroll
    for (int i = 0; i < 4; ++i) d[(ty + i * 8) * 1024 + tx] = f2bf(tile[tx][ty + i * 8]);
}

// ---------- transpose + convert w_o [1024][1024] -> [n][k] ----------
__global__ __launch_bounds__(256) void k_tcvt(const float* __restrict__ src,
                                              u16* __restrict__ dst, int R, int C) {
    __shared__ float tile[32][33];
    int r0 = blockIdx.x * 32, c0 = blockIdx.y * 32;
    int tx = threadIdx.x & 31, ty = threadIdx.x >> 5;
    const float* s = src + (size_t)r0 * C + c0;
#pragma unroll
    for (int i = 0; i < 4; ++i) tile[ty + i * 8][tx] = s[(ty + i * 8) * (size_t)C + tx];
    __syncthreads();
    u16* d = dst + (size_t)c0 * R + r0;
#pragma unroll
    for (int i = 0; i < 4; ++i) d[(ty + i * 8) * (size_t)R + tx] = f2bf(tile[tx][ty + i * 8]);
}

// ---------- mask bit-pack: mask[b][q][k] int32 -> mask64[b][kt][q] uint64 ----------
__global__ __launch_bounds__(256) void k_packmask(const int* __restrict__ mask,
                                                  u64* __restrict__ mask64) {
    int bid = blockIdx.x;  // 2 b x 512 q4 x 8 ktg
    int ktg = bid & 7, q4 = (bid >> 3) & 511, b = bid >> 12;
    int wave = threadIdx.x >> 6, lane = threadIdx.x & 63;
    int q = q4 * 4 + wave;
    const int* mp = mask + ((size_t)(b * 2048 + q)) * 2048 + ktg * 256 + lane;
#pragma unroll
    for (int i = 0; i < 4; ++i) {
        int m = mp[i * 64];
        u64 bal = __ballot(m != 0);
        if (lane == 0) mask64[((size_t)(b * 32 + ktg * 4 + i)) * 2048 + q] = bal;
    }
}

// ---------- GEMM core body (uses As, Bs u16* into shared) ----------
#define GEMM_CORE(Ablk, Bblk, ACC)                                                    \
    int c0 = wave * 2;                                                                \
    const u16* Ag0 = Ablk + (size_t)(c0 * 16 + l15) * 1024 + quad * 8;                \
    const u16* Ag1 = Ablk + (size_t)((c0 + 1) * 16 + l15) * 1024 + quad * 8;          \
    const u16* Bg0 = Bblk + (size_t)(c0 * 16 + l15) * 1024 + quad * 8;                \
    const u16* Bg1 = Bblk + (size_t)((c0 + 1) * 16 + l15) * 1024 + quad * 8;          \
    gld16(Ag0, As + c0 * 512); gld16(Ag1, As + (c0 + 1) * 512);                       \
    gld16(Bg0, Bs + c0 * 512); gld16(Bg1, Bs + (c0 + 1) * 512);                       \
    __syncthreads();                                                                  \
    int buf = 0;                                                                      \
    for (int ks = 0; ks < 32; ++ks) {                                                 \
        if (ks < 31) {                                                                \
            int k0 = (ks + 1) * 32;                                                   \
            gld16(Ag0 + k0, As + (buf ^ 1) * 4096 + c0 * 512);                        \
            gld16(Ag1 + k0, As + (buf ^ 1) * 4096 + (c0 + 1) * 512);                  \
            gld16(Bg0 + k0, Bs + (buf ^ 1) * 4096 + c0 * 512);                        \
            gld16(Bg1 + k0, Bs + (buf ^ 1) * 4096 + (c0 + 1) * 512);                  \
        }                                                                             \
        bf16x8 af[4], bfr[4];                                                         \
        _Pragma("unroll")                                                             \
        for (int i = 0; i < 4; ++i)                                                   \
            af[i] = *(const bf16x8*)(As + buf * 4096 + (wy * 4 + i) * 512 + lane * 8);\
        _Pragma("unroll")                                                             \
        for (int j = 0; j < 4; ++j)                                                   \
            bfr[j] = *(const bf16x8*)(Bs + buf * 4096 + (wx * 4 + j) * 512 + lane * 8);\
        _Pragma("unroll")                                                             \
        for (int i = 0; i < 4; ++i)                                                   \
            _Pragma("unroll")                                                         \
            for (int j = 0; j < 4; ++j) ACC[i][j] = MFMA16(af[i], bfr[j], ACC[i][j]); \
        __syncthreads();                                                              \
        buf ^= 1;                                                                     \
    }

// ---------- fused q/k/v projections, coalesced epilogue via LDS ----------
// z=0: qh (scaled by log2e/8), z=1: kh, z=2: vt = Wv@vb^T
__global__ __launch_bounds__(256) void k_proj(
    const u16* __restrict__ qb, const u16* __restrict__ kb, const u16* __restrict__ vb,
    const u16* __restrict__ wqt, const u16* __restrict__ wkt, const u16* __restrict__ wvt,
    u16* __restrict__ oq, u16* __restrict__ okh, u16* __restrict__ ovt) {
    __shared__ __align__(16) u16 smem[18432];
    u16* As = smem;
    u16* Bs = smem + 8192;
    int z = blockIdx.y, gx = blockIdx.x;
    int bm, bn;
    const u16 *A, *B;
    if (z == 0)      { bm = gx >> 3; bn = gx & 7; A = qb; B = wqt; }
    else if (z == 1) { bm = gx >> 3; bn = gx & 7; A = kb; B = wkt; }
    else             { bm = gx & 7; bn = gx >> 3; A = wvt; B = vb; }
    A += (size_t)bm * 128 * 1024;
    B += (size_t)bn * 128 * 1024;
    int tid = threadIdx.x, wave = tid >> 6, lane = tid & 63;
    int wy = wave >> 1, wx = wave & 1, l15 = lane & 15, quad = lane >> 4;
    f32x4 acc[4][4] = {};
    GEMM_CORE(A, B, acc)
    // epilogue: wave tile 64x64 -> LDS (stride 72) -> coalesced dwordx4 stores
    u16* ep = smem + wave * 4608;
    float mulf = (z == 0) ? 0.18033688011112042f : 1.0f;
#pragma unroll
    for (int i = 0; i < 4; ++i)
#pragma unroll
        for (int j = 0; j < 4; ++j)
#pragma unroll
            for (int r = 0; r < 4; ++r)
                ep[(i * 16 + quad * 4 + r) * 72 + j * 16 + l15] = f2bf(acc[i][j][r] * mulf);
    int rl = lane >> 3, cg = lane & 7;
    if (z < 2) {
        int hh = bn * 2 + wx;
        int m0 = bm * 128 + wy * 64;
        int bb = m0 >> 11, l0 = m0 & 2047;
        u16* O = (z ? okh : oq) + ((size_t)((hh * 2 + bb) * 2048 + l0)) * 64;
#pragma unroll
        for (int s = 0; s < 8; ++s) {
            int row = s * 8 + rl;
            uint4 v = *(const uint4*)(ep + row * 72 + cg * 8);
            *(uint4*)(O + (size_t)row * 64 + cg * 8) = v;
        }
    } else {
        int m0 = bm * 128 + wy * 64;   // e-global
        int hh = m0 >> 6;
        int n0 = bn * 128 + wx * 64;   // l-global
        int bb = n0 >> 11, l0 = n0 & 2047;
        u16* O = ovt + (size_t)(hh * 2 + bb) * 131072 + (size_t)(m0 & 63) * 2048 + l0;
#pragma unroll
        for (int s = 0; s < 8; ++s) {
            int row = s * 8 + rl;      // e within tile
            uint4 v = *(const uint4*)(ep + row * 72 + cg * 8);
            *(uint4*)(O + (size_t)row * 2048 + cg * 8) = v;
        }
    }
}

// ---------- output projection + bias + residual, coalesced epilogue ----------
__global__ __launch_bounds__(256) void k_out(
    const u16* __restrict__ ao, const u16* __restrict__ wot,
    const float* __restrict__ bo, const float* __restrict__ resid,
    float* __restrict__ xb) {
    __shared__ __align__(16) u16 smem[18432];
    u16* As = smem;
    u16* Bs = smem + 8192;
    int gx = blockIdx.x, bm = gx >> 3, bn = gx & 7;
    const u16* A = ao + (size_t)bm * 128 * 1024;
    const u16* B = wot + (size_t)bn * 128 * 1024;
    int tid = threadIdx.x, wave = tid >> 6, lane = tid & 63;
    int wy = wave >> 1, wx = wave & 1, l15 = lane & 15, quad = lane >> 4;
    f32x4 acc[4][4] = {};
    GEMM_CORE(A, B, acc)
    // epilogue fp32: two chunks of 32 rows x 64 cols via LDS (stride 68 f32)
    float* epf = (float*)(smem) + wave * 2176;
    int cgf = lane & 15, rlf = lane >> 4;
    int mbase = bm * 128 + wy * 64, nbase = bn * 128 + wx * 64;
#pragma unroll
    for (int cc = 0; cc < 2; ++cc) {
#pragma unroll
        for (int i2 = 0; i2 < 2; ++i2)
#pragma unroll
            for (int j = 0; j < 4; ++j)
#pragma unroll
                for (int r = 0; r < 4; ++r)
                    epf[(i2 * 16 + quad * 4 + r) * 68 + j * 16 + l15] =
                        acc[cc * 2 + i2][j][r];
#pragma unroll
        for (int s = 0; s < 8; ++s) {
            int row = s * 4 + rlf;
            f32x4 v = *(const f32x4*)(epf + row * 68 + cgf * 4);
            int m = mbase + cc * 32 + row, n = nbase + cgf * 4;
            float4 rsd = *(const float4*)(resid + (size_t)m * 1024 + n);
            float4 bo4 = *(const float4*)(bo + n);
            float4 o;
            o.x = v[0] + bo4.x + rsd.x;
            o.y = v[1] + bo4.y + rsd.y;
            o.z = v[2] + bo4.z + rsd.z;
            o.w = v[3] + bo4.w + rsd.w;
            *(float4*)(xb + (size_t)m * 1024 + n) = o;
        }
        // wave-local LDS reuse between chunks; same-wave DS ordering suffices
    }
}

// ---------- flash attention: fixed-shift softmax, 128 Q-rows/block ----------
// grid (16 qt, 32 hb), block 512 = 8 waves; Q pre-scaled by log2e/8 so p = exp2(st)
__global__ __launch_bounds__(512) void k_attn(
    const u16* __restrict__ qh, const u16* __restrict__ kh,
    const u16* __restrict__ vt, const u64* __restrict__ mask64,
    u16* __restrict__ ao) {
    int qt = blockIdx.x, hb = blockIdx.y;
    int h = hb >> 1, b = hb & 1;
    int tid = threadIdx.x, wave = tid >> 6, lane = tid & 63;
    int l15 = lane & 15, quad = lane >> 4;

    __shared__ __align__(16) u16 Ks[2][4096], Vs[2][4096];
    __shared__ __align__(16) u16 Pb[8][16][72];

    int qrow0 = qt * 128 + wave * 16;
    const u16* Qp = qh + ((size_t)(hb * 2048) + qrow0 + l15) * 64 + quad * 8;
    bf16x8 qf0 = *(const bf16x8*)Qp;
    bf16x8 qf1 = *(const bf16x8*)(Qp + 32);

    int tK = wave >> 1, hK = wave & 1;
    const u16* Kg = kh + (size_t)hb * 131072 + (size_t)(tK * 16 + l15) * 64 + hK * 32 + quad * 8;
    const u16* Vg = vt + (size_t)hb * 131072 + (size_t)(tK * 16 + l15) * 2048 + hK * 32 + quad * 8;
    const u64* Mp = mask64 + (size_t)b * 65536 + qrow0 + l15;

    float l_lane = 0.f;   // per-lane partial row sum (row l15, this lane's 16 kcols)
    f32x4 o[4] = {};

    gld16(Kg, &Ks[0][wave * 512]);
    gld16(Vg, &Vs[0][wave * 512]);
    u64 mw_cur = Mp[0];
    __syncthreads();
    int buf = 0;
    for (int kt = 0; kt < 32; ++kt) {
        u64 mw_nxt = 0;
        if (kt < 31) {
            gld16(Kg + (size_t)(kt + 1) * 4096, &Ks[buf ^ 1][wave * 512]);
            gld16(Vg + (size_t)(kt + 1) * 64, &Vs[buf ^ 1][wave * 512]);
            mw_nxt = Mp[(size_t)(kt + 1) * 2048];
        }
        // ---- S^T: lane = (qrow=l15, kcol = t*16 + quad*4 + r) ----
        f32x4 st[4] = {};
#pragma unroll
        for (int t = 0; t < 4; ++t) {
            bf16x8 k0 = *(const bf16x8*)&Ks[buf][(t * 2 + 0) * 512 + lane * 8];
            bf16x8 k1 = *(const bf16x8*)&Ks[buf][(t * 2 + 1) * 512 + lane * 8];
            st[t] = MFMA16(k0, qf0, st[t]);
            st[t] = MFMA16(k1, qf1, st[t]);
        }
        // ---- mask ----
        unsigned int w0 = (unsigned int)(mw_cur >> (quad * 4));
        unsigned int w1 = (unsigned int)(mw_cur >> (32 + quad * 4));
#pragma unroll
        for (int r = 0; r < 4; ++r) {
            st[0][r] = ((w0 >> r) & 1u) ? -3e30f : st[0][r];
            st[1][r] = ((w0 >> (16 + r)) & 1u) ? -3e30f : st[1][r];
            st[2][r] = ((w1 >> r) & 1u) ? -3e30f : st[2][r];
            st[3][r] = ((w1 >> (16 + r)) & 1u) ? -3e30f : st[3][r];
        }
        // ---- p = exp2(st) (fixed shift), accumulate l, pack bf16 -> Pb ----
#pragma unroll
        for (int t = 0; t < 4; ++t) {
            float p0 = __builtin_amdgcn_exp2f(st[t][0]);
            float p1 = __builtin_amdgcn_exp2f(st[t][1]);
            float p2 = __builtin_amdgcn_exp2f(st[t][2]);
            float p3 = __builtin_amdgcn_exp2f(st[t][3]);
            l_lane += (p0 + p1) + (p2 + p3);
            uint2 pk;
            pk.x = (__float_as_uint(p1) & 0xffff0000u) | (__float_as_uint(p0) >> 16);
            pk.y = (__float_as_uint(p3) & 0xffff0000u) | (__float_as_uint(p2) >> 16);
            *(uint2*)&Pb[wave][l15][t * 16 + quad * 4] = pk;
        }
        // ---- O += P @ V ----
#pragma unroll
        for (int kc = 0; kc < 2; ++kc) {
            bf16x8 pf = *(const bf16x8*)&Pb[wave][l15][kc * 32 + quad * 8];
#pragma unroll
            for (int t = 0; t < 4; ++t) {
                bf16x8 vf = *(const bf16x8*)&Vs[buf][(t * 2 + kc) * 512 + lane * 8];
                o[t] = MFMA16(pf, vf, o[t]);
            }
        }
        mw_cur = mw_nxt;
        __syncthreads();
        buf ^= 1;
    }
    // ---- final l reduction + normalize ----
    float ls = l_lane;
    ls += __shfl_xor(ls, 16, 64);
    ls += __shfl_xor(ls, 32, 64);
    float inv = 1.0f / ls;          // inv for qrow = l15
    f32x4 ivr;
#pragma unroll
    for (int r = 0; r < 4; ++r) ivr[r] = __shfl(inv, quad * 4 + r, 16);
    // store via Pb for coalesced dwordx4 writes
#pragma unroll
    for (int t = 0; t < 4; ++t)
#pragma unroll
        for (int r = 0; r < 4; ++r)
            Pb[wave][quad * 4 + r][t * 16 + l15] = f2bf(o[t][r] * ivr[r]);
    int rl = lane >> 3, cg = lane & 7;
#pragma unroll
    for (int s = 0; s < 2; ++s) {
        int row = s * 8 + rl;
        uint4 v = *(const uint4*)&Pb[wave][row][cg * 8];
        *(uint4*)(ao + ((size_t)(b * 2048 + qrow0 + row)) * 1024 + h * 64 + cg * 8) = v;
    }
}

// ---------- layernorm (torch: std ddof=1, eps on std) ----------
__global__ __launch_bounds__(256) void k_ln(const float* __restrict__ x,
                                            const float* __restrict__ gamma,
                                            const float* __restrict__ beta,
                                            float* __restrict__ out) {
    int row = blockIdx.x;
    const float* xr = x + (size_t)row * 1024;
    float4 v = ((const float4*)xr)[threadIdx.x];
    float s = v.x + v.y + v.z + v.w;
    float ss = v.x * v.x + v.y * v.y + v.z * v.z + v.w * v.w;
#pragma unroll
    for (int off = 32; off; off >>= 1) {
        s += __shfl_down(s, off, 64);
        ss += __shfl_down(ss, off, 64);
    }
    __shared__ float sb[8];
    int wave = threadIdx.x >> 6, lane = threadIdx.x & 63;
    if (lane == 0) { sb[wave] = s; sb[4 + wave] = ss; }
    __syncthreads();
    s = sb[0] + sb[1] + sb[2] + sb[3];
    ss = sb[4] + sb[5] + sb[6] + sb[7];
    float mean = s * (1.0f / 1024.0f);
    float var = fmaxf((ss - 1024.0f * mean * mean) * (1.0f / 1023.0f), 0.f);
    float inv = 1.0f / (sqrtf(var) + 1e-3f);
    float4 g = ((const float4*)gamma)[threadIdx.x];
    float4 bt = ((const float4*)beta)[threadIdx.x];
    float4 o;
    o.x = (v.x - mean) * inv * g.x + bt.x;
    o.y = (v.y - mean) * inv * g.y + bt.y;
    o.z = (v.z - mean) * inv * g.z + bt.z;
    o.w = (v.w - mean) * inv * g.w + bt.w;
    ((float4*)(out + (size_t)row * 1024))[threadIdx.x] = o;
}

// ---------- launch ----------
extern "C" void kernel_launch(void* const* d_in, const int* in_sizes, int n_in,
                              void* d_out, int out_size, void* d_ws, size_t ws_size,
                              hipStream_t stream) {
    const float* v_in  = (const float*)d_in[0];
    const float* k_in  = (const float*)d_in[1];
    const float* q_in  = (const float*)d_in[2];
    const int*   mask  = (const int*)d_in[3];
    const float* w_q   = (const float*)d_in[4];
    const float* w_k   = (const float*)d_in[5];
    const float* w_v   = (const float*)d_in[6];
    const float* w_o   = (const float*)d_in[7];
    const float* b_o   = (const float*)d_in[8];
    const float* gamma = (const float*)d_in[9];
    const float* beta  = (const float*)d_in[10];
    float* out = (float*)d_out;

    char* ws = (char*)d_ws;
    const size_t MB = 1ull << 20;
    u16* qb  = (u16*)(ws + 0 * MB);
    u16* kb  = (u16*)(ws + 8 * MB);
    u16* vb  = (u16*)(ws + 16 * MB);
    u16* wqt = (u16*)(ws + 24 * MB);
    u16* wkt = (u16*)(ws + 26 * MB);
    u16* wvt = (u16*)(ws + 28 * MB);
    u16* wot = (u16*)(ws + 30 * MB);
    u16* qh  = (u16*)(ws + 32 * MB);
    u16* kh  = (u16*)(ws + 40 * MB);
    u16* vt  = (u16*)(ws + 48 * MB);
    u16* ao  = (u16*)(ws + 56 * MB);
    u64* mask64 = (u64*)(ws + 64 * MB);  // dead before xb written
    float* xb = (float*)(ws + 64 * MB);

    k_cvt3<<<dim3(4096, 3), dim3(256), 0, stream>>>(q_in, k_in, v_in, qb, kb, vb);
    k_tcvt3<<<dim3(32, 2, 48), dim3(256), 0, stream>>>(w_q, w_k, w_v, wqt, wkt, wvt);
    k_tcvt<<<dim3(32, 32), dim3(256), 0, stream>>>(w_o, wot, 1024, 1024);
    k_packmask<<<dim3(8192), dim3(256), 0, stream>>>(mask, mask64);
    k_proj<<<dim3(256, 3), dim3(256), 0, stream>>>(qb, kb, vb, wqt, wkt, wvt, qh, kh, vt);
    k_attn<<<dim3(16, 32), dim3(512), 0, stream>>>(qh, kh, vt, mask64, ao);
    k_out<<<dim3(256), dim3(256), 0, stream>>>(ao, wot, b_o, k_in, xb);
    k_ln<<<dim3(4096), dim3(256), 0, stream>>>(xb, gamma, beta, out);
}